// Round 6
// baseline (17.885 us; speedup 1.0000x reference)
//
#include <hip/hip_runtime.h>
#include <math.h>

#define RW 256          // render width  (u axis, output axis 0)
#define RH 256          // render height (v axis, output axis 1)
#define VN 256          // volume resolution per axis
#define TFN 128
#define MAXS 256

struct Slot { float2 A, B, C, D; float fx, fy, fz; };

__global__ __launch_bounds__(256, 1) void raycast_kernel(
    const float* __restrict__ vol,   // (256,256,256) row-major: x*65536+y*256+z
    const float4* __restrict__ tf,   // (128,4)
    const float* __restrict__ lf3,   // (3,)
    float4* __restrict__ out)        // (256,256,4)
{
    __shared__ float4 tf_s[TFN];
    if (threadIdx.x < TFN) tf_s[threadIdx.x] = tf[threadIdx.x];
    __syncthreads();

    // 8x8 pixel tile per wave: block = 16x16 pixels, 4 waves.
    // lane&7 -> py (output fast axis) so the final float4 store is
    // 128B-contiguous per 8-lane group (was 4KB-strided).
    const int lane = threadIdx.x & 63;
    const int wid  = threadIdx.x >> 6;
    const int ty = (wid & 1) * 8 + (lane & 7);
    const int tx = (wid >> 1) * 8 + (lane >> 3);
    const int px = blockIdx.x * 16 + tx;   // u / output axis 0
    const int py = blockIdx.y * 16 + ty;   // v / output axis 1

    const float lfx = lf3[0], lfy = lf3[1], lfz = lf3[2];

    // view_dir = normalize(-look_from)
    float inv = rsqrtf(lfx * lfx + lfy * lfy + lfz * lfz);
    const float vdx = -lfx * inv, vdy = -lfy * inv, vdz = -lfz * inv;

    // right = normalize(cross(view_dir, (0,1,0))) = normalize((-vdz, 0, vdx))
    float rx = -vdz, rz = vdx;
    inv = rsqrtf(rx * rx + rz * rz);
    rx *= inv; rz *= inv;

    // up = normalize(cross(right, view_dir));  right.y == 0
    float ux = -rz * vdy;
    float uy = rz * vdx - rx * vdz;
    float uz = rx * vdy;
    inv = rsqrtf(ux * ux + uy * uy + uz * uz);
    ux *= inv; uy *= inv; uz *= inv;

    const float NEAR = 0.1f;
    const float near_h = 2.0f * tanf(0.5235987755982988f) * NEAR; // fov=30deg
    const float near_w = near_h;  // aspect = 1

    const float u = ((float)px + 0.5f) / (float)RW - 0.5f;
    const float v = ((float)py + 0.5f) / (float)RH - 0.5f;

    float rdx = NEAR * vdx + u * near_w * rx + v * near_h * ux;
    float rdy = NEAR * vdy              + v * near_h * uy;   // right.y == 0
    float rdz = NEAR * vdz + u * near_w * rz + v * near_h * uz;
    inv = rsqrtf(rdx * rdx + rdy * rdy + rdz * rdz);
    rdx *= inv; rdy *= inv; rdz *= inv;

    // slab test against [-1,1]^3
    const float sdx = (fabsf(rdx) < 1e-9f) ? 1e-9f : rdx;
    const float sdy = (fabsf(rdy) < 1e-9f) ? 1e-9f : rdy;
    const float sdz = (fabsf(rdz) < 1e-9f) ? 1e-9f : rdz;
    const float dfx = 1.0f / sdx, dfy = 1.0f / sdy, dfz = 1.0f / sdz;
    const float t1x = (-1.0f - lfx) * dfx, t2x = (1.0f - lfx) * dfx;
    const float t1y = (-1.0f - lfy) * dfy, t2y = (1.0f - lfy) * dfy;
    const float t1z = (-1.0f - lfz) * dfz, t2z = (1.0f - lfz) * dfz;
    const float tmin = fmaxf(fminf(t1x, t2x), fmaxf(fminf(t1y, t2y), fminf(t1z, t2z)));
    const float tmax = fminf(fmaxf(t1x, t2x), fminf(fmaxf(t1y, t2y), fmaxf(t1z, t2z)));
    const bool hit = (tmax >= 0.0f) && (tmin <= tmax);
    const float entry = fmaxf(tmin, 0.0f);
    const float ray_len = fmaxf(tmax - entry, 0.0f);

    // n_samples = clip(ceil(VOL_DIAG * ray_len / 2), 1, 256); VOL_DIAG = 256*sqrt(3)
    const float nsf = fminf(fmaxf(ceilf(443.4050067376326f * ray_len / 2.0f), 1.0f),
                            (float)MAXS);
    const int n = (int)nsf;
    const float dt = ray_len / nsf;

    float acc_r = 0.0f, acc_g = 0.0f, acc_b = 0.0f, acc_a = 0.0f;

    if (hit) {
        const float scale = 255.0f - 1e-4f;  // (shp-1-1e-4) => p < 255, hi never clamps
        // Positions are clamped to the volume, so issuing ANY k is address-safe;
        // speculative issues load garbage that is never consumed (masked to w=0).
        auto issue = [&](int k) -> Slot {
            Slot s;
            const float t = entry + ((float)k + 0.5f) * dt;
            const float posx = lfx + rdx * t;
            const float posy = lfy + rdy * t;
            const float posz = lfz + rdz * t;
            const float pxf = fminf(fmaxf(0.5f * posx + 0.5f, 0.0f), 1.0f) * scale;
            const float pyf = fminf(fmaxf(0.5f * posy + 0.5f, 0.0f), 1.0f) * scale;
            const float pzf = fminf(fmaxf(0.5f * posz + 0.5f, 0.0f), 1.0f) * scale;
            const float flx = floorf(pxf), fly = floorf(pyf), flz = floorf(pzf);
            s.fx = pxf - flx; s.fy = pyf - fly; s.fz = pzf - flz;
            const int x0 = (int)flx, y0 = (int)fly, z0 = (int)flz;
            const float* p = vol + ((x0 << 16) + (y0 << 8) + z0);
            s.A = *(const float2*)p;                   // c000, c001
            s.B = *(const float2*)(p + 65536);         // c100, c101
            s.C = *(const float2*)(p + 256);           // c010, c011
            s.D = *(const float2*)(p + 65536 + 256);   // c110, c111
            return s;
        };
        auto trilerp = [&](const Slot& s) -> float {
            const float c00 = s.A.x * (1.0f - s.fx) + s.B.x * s.fx;
            const float c10 = s.C.x * (1.0f - s.fx) + s.D.x * s.fx;
            const float c01 = s.A.y * (1.0f - s.fx) + s.B.y * s.fx;
            const float c11 = s.C.y * (1.0f - s.fx) + s.D.y * s.fx;
            const float c0 = c00 * (1.0f - s.fy) + c10 * s.fy;
            const float c1 = c01 * (1.0f - s.fy) + c11 * s.fy;
            return c0 * (1.0f - s.fz) + c1 * s.fz;
        };
        auto tflookup = [&](float intensity) -> float4 {
            const float ti = fminf(fmaxf(intensity, 0.0f), 1.0f) * (float)(TFN - 1);
            const float tl = floorf(ti);
            const float tfr = ti - tl;
            const int i0 = (int)tl;
            const int i1 = min(i0 + 1, TFN - 1);
            const float om = 1.0f - tfr;
            const float4 tlo = tf_s[i0];
            const float4 thi = tf_s[i1];
            float4 o;
            o.x = tlo.x * om + thi.x * tfr;
            o.y = tlo.y * om + thi.y * tfr;
            o.z = tlo.z * om + thi.z * tfr;
            o.w = tlo.w * om + thi.w * tfr;
            return o;
        };

        // Consume a PAIR of samples (kc, kc+1) in straight-line code:
        // the two trilinear chains and the two TF LDS lookups are independent
        // and overlap; only the short composite chain is serial.
        #define CONSUME_PAIR(sa, sb, kc_)                                     \
        {                                                                     \
            const float ia = trilerp(sa);                                     \
            const float ib = trilerp(sb);                                     \
            const float4 ca = tflookup(ia);                                   \
            const float4 cb = tflookup(ib);                                   \
            const float alpha_a = 1.0f - fmaxf(1.0f - ca.w, 1e-7f);           \
            const float wa = (1.0f - acc_a) * alpha_a;                        \
            acc_r += wa * ca.x; acc_g += wa * ca.y; acc_b += wa * ca.z;       \
            acc_a += wa;                                                      \
            const bool vb = (((kc_) + 1) < n) && (acc_a < 0.99f);             \
            const float alpha_b = vb ? (1.0f - fmaxf(1.0f - cb.w, 1e-7f))     \
                                     : 0.0f;                                  \
            const float wb = (1.0f - acc_a) * alpha_b;                        \
            acc_r += wb * cb.x; acc_g += wb * cb.y; acc_b += wb * cb.z;       \
            acc_a += wb;                                                      \
        }

        // depth-8 rolling load pipeline, break check every 2 samples
        Slot s0 = issue(0), s1 = issue(1), s2 = issue(2), s3 = issue(3);
        Slot s4 = issue(4), s5 = issue(5), s6 = issue(6), s7 = issue(7);
        int kc = 0;   // slots hold samples kc..kc+7; kc < n on entry
        while (true) {
            CONSUME_PAIR(s0, s1, kc); kc += 2;
            if (kc >= n || acc_a >= 0.99f) break;
            s0 = issue(kc + 6); s1 = issue(kc + 7);

            CONSUME_PAIR(s2, s3, kc); kc += 2;
            if (kc >= n || acc_a >= 0.99f) break;
            s2 = issue(kc + 6); s3 = issue(kc + 7);

            CONSUME_PAIR(s4, s5, kc); kc += 2;
            if (kc >= n || acc_a >= 0.99f) break;
            s4 = issue(kc + 6); s5 = issue(kc + 7);

            CONSUME_PAIR(s6, s7, kc); kc += 2;
            if (kc >= n || acc_a >= 0.99f) break;
            s6 = issue(kc + 6); s7 = issue(kc + 7);
        }
        #undef CONSUME_PAIR
    }

    float4 o4;
    o4.x = acc_r; o4.y = acc_g; o4.z = acc_b; o4.w = acc_a;
    out[px * RH + py] = o4;
}

extern "C" void kernel_launch(void* const* d_in, const int* in_sizes, int n_in,
                              void* d_out, int out_size, void* d_ws, size_t ws_size,
                              hipStream_t stream) {
    const float* vol = (const float*)d_in[0];
    const float4* tf = (const float4*)d_in[1];
    const float* lf  = (const float*)d_in[2];
    float4* out = (float4*)d_out;

    dim3 grid(RW / 16, RH / 16);   // 16x16 pixel tiles, 256 threads each
    raycast_kernel<<<grid, 256, 0, stream>>>(vol, tf, lf, out);
}

// Round 7
// 11.303 us; speedup vs baseline: 1.5823x; 1.5823x over previous
//
#include <hip/hip_runtime.h>
#include <math.h>

#define RW 256          // render width  (u axis, output axis 0)
#define RH 256          // render height (v axis, output axis 1)
#define VN 256          // volume resolution per axis
#define TFN 128
#define MAXS 256

struct Slot { float2 A, B, C, D; float fx, fy, fz; };

__global__ __launch_bounds__(256, 1) void raycast_kernel(
    const float* __restrict__ vol,   // (256,256,256) row-major: x*65536+y*256+z
    const float4* __restrict__ tf,   // (128,4)
    const float* __restrict__ lf3,   // (3,)
    float4* __restrict__ out)        // (256,256,4)
{
    __shared__ float4 tf_s[TFN];
    if (threadIdx.x < TFN) tf_s[threadIdx.x] = tf[threadIdx.x];
    __syncthreads();

    // 8x8 pixel tile per wave: block = 16x16 pixels, 4 waves.
    // lane&7 -> px: u-adjacent rays share cache lines along the z fast axis
    // (measured: px-fast 12.6us vs py-fast 17.9us — gathers dominate stores).
    const int lane = threadIdx.x & 63;
    const int wid  = threadIdx.x >> 6;
    const int tx = (wid & 1) * 8 + (lane & 7);
    const int ty = (wid >> 1) * 8 + (lane >> 3);
    const int px = blockIdx.x * 16 + tx;   // u / output axis 0
    const int py = blockIdx.y * 16 + ty;   // v / output axis 1

    const float lfx = lf3[0], lfy = lf3[1], lfz = lf3[2];

    // view_dir = normalize(-look_from)
    float inv = rsqrtf(lfx * lfx + lfy * lfy + lfz * lfz);
    const float vdx = -lfx * inv, vdy = -lfy * inv, vdz = -lfz * inv;

    // right = normalize(cross(view_dir, (0,1,0))) = normalize((-vdz, 0, vdx))
    float rx = -vdz, rz = vdx;
    inv = rsqrtf(rx * rx + rz * rz);
    rx *= inv; rz *= inv;

    // up = normalize(cross(right, view_dir));  right.y == 0
    float ux = -rz * vdy;
    float uy = rz * vdx - rx * vdz;
    float uz = rx * vdy;
    inv = rsqrtf(ux * ux + uy * uy + uz * uz);
    ux *= inv; uy *= inv; uz *= inv;

    const float NEAR = 0.1f;
    const float near_h = 2.0f * tanf(0.5235987755982988f) * NEAR; // fov=30deg
    const float near_w = near_h;  // aspect = 1

    const float u = ((float)px + 0.5f) / (float)RW - 0.5f;
    const float v = ((float)py + 0.5f) / (float)RH - 0.5f;

    float rdx = NEAR * vdx + u * near_w * rx + v * near_h * ux;
    float rdy = NEAR * vdy              + v * near_h * uy;   // right.y == 0
    float rdz = NEAR * vdz + u * near_w * rz + v * near_h * uz;
    inv = rsqrtf(rdx * rdx + rdy * rdy + rdz * rdz);
    rdx *= inv; rdy *= inv; rdz *= inv;

    // slab test against [-1,1]^3
    const float sdx = (fabsf(rdx) < 1e-9f) ? 1e-9f : rdx;
    const float sdy = (fabsf(rdy) < 1e-9f) ? 1e-9f : rdy;
    const float sdz = (fabsf(rdz) < 1e-9f) ? 1e-9f : rdz;
    const float dfx = 1.0f / sdx, dfy = 1.0f / sdy, dfz = 1.0f / sdz;
    const float t1x = (-1.0f - lfx) * dfx, t2x = (1.0f - lfx) * dfx;
    const float t1y = (-1.0f - lfy) * dfy, t2y = (1.0f - lfy) * dfy;
    const float t1z = (-1.0f - lfz) * dfz, t2z = (1.0f - lfz) * dfz;
    const float tmin = fmaxf(fminf(t1x, t2x), fmaxf(fminf(t1y, t2y), fminf(t1z, t2z)));
    const float tmax = fminf(fmaxf(t1x, t2x), fminf(fmaxf(t1y, t2y), fmaxf(t1z, t2z)));
    const bool hit = (tmax >= 0.0f) && (tmin <= tmax);
    const float entry = fmaxf(tmin, 0.0f);
    const float ray_len = fmaxf(tmax - entry, 0.0f);

    // n_samples = clip(ceil(VOL_DIAG * ray_len / 2), 1, 256); VOL_DIAG = 256*sqrt(3)
    const float nsf = fminf(fmaxf(ceilf(443.4050067376326f * ray_len / 2.0f), 1.0f),
                            (float)MAXS);
    const int n = (int)nsf;
    const float dt = ray_len / nsf;

    float acc_r = 0.0f, acc_g = 0.0f, acc_b = 0.0f, acc_a = 0.0f;

    if (hit) {
        const float scale = 255.0f - 1e-4f;  // (shp-1-1e-4) => p < 255, hi never clamps
        // Positions are clamped to the volume, so issuing ANY k is address-safe;
        // speculative issues load garbage that is never consumed (masked to w=0).
        auto issue = [&](int k) -> Slot {
            Slot s;
            const float t = entry + ((float)k + 0.5f) * dt;
            const float posx = lfx + rdx * t;
            const float posy = lfy + rdy * t;
            const float posz = lfz + rdz * t;
            const float pxf = fminf(fmaxf(0.5f * posx + 0.5f, 0.0f), 1.0f) * scale;
            const float pyf = fminf(fmaxf(0.5f * posy + 0.5f, 0.0f), 1.0f) * scale;
            const float pzf = fminf(fmaxf(0.5f * posz + 0.5f, 0.0f), 1.0f) * scale;
            const float flx = floorf(pxf), fly = floorf(pyf), flz = floorf(pzf);
            s.fx = pxf - flx; s.fy = pyf - fly; s.fz = pzf - flz;
            const int x0 = (int)flx, y0 = (int)fly, z0 = (int)flz;
            const float* p = vol + ((x0 << 16) + (y0 << 8) + z0);
            s.A = *(const float2*)p;                   // c000, c001
            s.B = *(const float2*)(p + 65536);         // c100, c101
            s.C = *(const float2*)(p + 256);           // c010, c011
            s.D = *(const float2*)(p + 65536 + 256);   // c110, c111
            return s;
        };
        auto trilerp = [&](const Slot& s) -> float {
            const float c00 = s.A.x * (1.0f - s.fx) + s.B.x * s.fx;
            const float c10 = s.C.x * (1.0f - s.fx) + s.D.x * s.fx;
            const float c01 = s.A.y * (1.0f - s.fx) + s.B.y * s.fx;
            const float c11 = s.C.y * (1.0f - s.fx) + s.D.y * s.fx;
            const float c0 = c00 * (1.0f - s.fy) + c10 * s.fy;
            const float c1 = c01 * (1.0f - s.fy) + c11 * s.fy;
            return c0 * (1.0f - s.fz) + c1 * s.fz;
        };
        auto tflookup = [&](float intensity) -> float4 {
            const float ti = fminf(fmaxf(intensity, 0.0f), 1.0f) * (float)(TFN - 1);
            const float tl = floorf(ti);
            const float tfr = ti - tl;
            const int i0 = (int)tl;
            const int i1 = min(i0 + 1, TFN - 1);
            const float om = 1.0f - tfr;
            const float4 tlo = tf_s[i0];
            const float4 thi = tf_s[i1];
            float4 o;
            o.x = tlo.x * om + thi.x * tfr;
            o.y = tlo.y * om + thi.y * tfr;
            o.z = tlo.z * om + thi.z * tfr;
            o.w = tlo.w * om + thi.w * tfr;
            return o;
        };

        // Consume a PAIR of samples (kc, kc+1) in straight-line code:
        // the two trilinear chains and the two TF LDS lookups are independent
        // and overlap; only the short composite chain is serial.
        #define CONSUME_PAIR(sa, sb, kc_)                                     \
        {                                                                     \
            const float ia = trilerp(sa);                                     \
            const float ib = trilerp(sb);                                     \
            const float4 ca = tflookup(ia);                                   \
            const float4 cb = tflookup(ib);                                   \
            const float alpha_a = 1.0f - fmaxf(1.0f - ca.w, 1e-7f);           \
            const float wa = (1.0f - acc_a) * alpha_a;                        \
            acc_r += wa * ca.x; acc_g += wa * ca.y; acc_b += wa * ca.z;       \
            acc_a += wa;                                                      \
            const bool vb = (((kc_) + 1) < n) && (acc_a < 0.99f);             \
            const float alpha_b = vb ? (1.0f - fmaxf(1.0f - cb.w, 1e-7f))     \
                                     : 0.0f;                                  \
            const float wb = (1.0f - acc_a) * alpha_b;                        \
            acc_r += wb * cb.x; acc_g += wb * cb.y; acc_b += wb * cb.z;       \
            acc_a += wb;                                                      \
        }

        // depth-8 rolling load pipeline, break check every 2 samples
        Slot s0 = issue(0), s1 = issue(1), s2 = issue(2), s3 = issue(3);
        Slot s4 = issue(4), s5 = issue(5), s6 = issue(6), s7 = issue(7);
        int kc = 0;   // slots hold samples kc..kc+7; kc < n on entry
        while (true) {
            CONSUME_PAIR(s0, s1, kc); kc += 2;
            if (kc >= n || acc_a >= 0.99f) break;
            s0 = issue(kc + 6); s1 = issue(kc + 7);

            CONSUME_PAIR(s2, s3, kc); kc += 2;
            if (kc >= n || acc_a >= 0.99f) break;
            s2 = issue(kc + 6); s3 = issue(kc + 7);

            CONSUME_PAIR(s4, s5, kc); kc += 2;
            if (kc >= n || acc_a >= 0.99f) break;
            s4 = issue(kc + 6); s5 = issue(kc + 7);

            CONSUME_PAIR(s6, s7, kc); kc += 2;
            if (kc >= n || acc_a >= 0.99f) break;
            s6 = issue(kc + 6); s7 = issue(kc + 7);
        }
        #undef CONSUME_PAIR
    }

    float4 o4;
    o4.x = acc_r; o4.y = acc_g; o4.z = acc_b; o4.w = acc_a;
    out[px * RH + py] = o4;
}

extern "C" void kernel_launch(void* const* d_in, const int* in_sizes, int n_in,
                              void* d_out, int out_size, void* d_ws, size_t ws_size,
                              hipStream_t stream) {
    const float* vol = (const float*)d_in[0];
    const float4* tf = (const float4*)d_in[1];
    const float* lf  = (const float*)d_in[2];
    float4* out = (float4*)d_out;

    dim3 grid(RW / 16, RH / 16);   // 16x16 pixel tiles, 256 threads each
    raycast_kernel<<<grid, 256, 0, stream>>>(vol, tf, lf, out);
}